// Round 3
// baseline (564.455 us; speedup 1.0000x reference)
//
#include <hip/hip_runtime.h>

typedef unsigned short ushort_t;
typedef __attribute__((ext_vector_type(8))) short short8;
typedef __attribute__((ext_vector_type(4))) float float4v;

__device__ inline float b2f(ushort_t u) {
    unsigned x = ((unsigned)u) << 16;
    return __builtin_bit_cast(float, x);
}
__device__ inline ushort_t f2b(float f) {
    unsigned x = __builtin_bit_cast(unsigned, f);
    unsigned r = (x + 0x7fffu + ((x >> 16) & 1u)) >> 16;
    return (ushort_t)r;
}

// ---------------- int64-vs-int32 edge_index layout detection ----------------
// int64 little-endian with values < 2^31 => every odd int32 slot is 0.

__global__ void k_mode(const int* __restrict__ ei, int E, int* mode) {
    __shared__ int any32;
    if (threadIdx.x == 0) any32 = 0;
    __syncthreads();
    for (int i = threadIdx.x; i < 1024; i += blockDim.x) {
        int slot = 2 * i + 1;
        if (slot < 2 * E && ei[slot] != 0) atomicOr(&any32, 1);
    }
    __syncthreads();
    if (threadIdx.x == 0) mode[0] = any32 ? 0 : 1;  // 1 => int64 layout
}

__device__ inline int ld_src(const int* __restrict__ ei, int e, int E, int m64) {
    return m64 ? ei[2 * (size_t)e] : ei[e];
}
__device__ inline int ld_dst(const int* __restrict__ ei, int e, int E, int m64) {
    return m64 ? ei[2 * ((size_t)E + e)] : ei[(size_t)E + e];
}

// ---------------- fp32 -> bf16 casts ----------------

__global__ void k_cast_x(const float* __restrict__ x, ushort_t* __restrict__ xb, int n4) {
    int i = blockIdx.x * blockDim.x + threadIdx.x;
    if (i >= n4) return;
    float4v v = ((const float4v*)x)[i];
    ushort4 o;
    o.x = f2b(v[0]); o.y = f2b(v[1]); o.z = f2b(v[2]); o.w = f2b(v[3]);
    ((ushort4*)xb)[i] = o;
}

__global__ void k_cast_w(const float* __restrict__ W1, const float* __restrict__ W2,
                         ushort_t* __restrict__ W1b, ushort_t* __restrict__ W2b) {
    int i = blockIdx.x * blockDim.x + threadIdx.x;  // 0..65535
    if (i < 32768) W1b[i] = f2b(W1[i]);
    else W2b[i - 32768] = f2b(W2[i - 32768]);
}

// ---------------- degree/CSR build ----------------

__global__ void k_node_init(float* degf, int* cnt, int Nn) {
    int i = blockIdx.x * blockDim.x + threadIdx.x;
    if (i < Nn) { degf[i] = 1.0f; cnt[i] = 0; }  // self-loop weight 1
}

__global__ void k_count(const int* __restrict__ ei, const float* __restrict__ w,
                        const int* __restrict__ mode,
                        float* degf, int* cnt, int E, int Nn) {
    int e = blockIdx.x * blockDim.x + threadIdx.x;
    if (e >= E) return;
    int m64 = mode[0];
    int s = ld_src(ei, e, E, m64);
    int d = ld_dst(ei, e, E, m64);
    if ((unsigned)s < (unsigned)Nn && (unsigned)d < (unsigned)Nn) {
        atomicAdd(cnt + d, 1);
        atomicAdd(degf + d, w[e]);
    }
}

__global__ __launch_bounds__(1024) void k_scan(const int* __restrict__ cnt,
                                               int* offs, int* cursor, int Nn) {
    __shared__ int sdata[1024];
    int t = threadIdx.x;
    int chunk = (Nn + 1023) / 1024;
    int lo = t * chunk, hi = min(Nn, lo + chunk);
    int s = 0;
    for (int i = lo; i < hi; ++i) s += cnt[i];
    sdata[t] = s;
    __syncthreads();
    for (int off = 1; off < 1024; off <<= 1) {
        int v = (t >= off) ? sdata[t - off] : 0;
        __syncthreads();
        sdata[t] += v;
        __syncthreads();
    }
    int run = sdata[t] - s;  // exclusive prefix
    for (int i = lo; i < hi; ++i) {
        offs[i] = run; cursor[i] = run;
        run += cnt[i];
    }
    if (t == 1023) offs[Nn] = run;
}

__global__ void k_dinv(float* degf, int Nn) {
    int i = blockIdx.x * blockDim.x + threadIdx.x;
    if (i < Nn) degf[i] = rsqrtf(degf[i]);  // deg >= 1 (self loop)
}

__global__ void k_scatter(const int* __restrict__ ei, const float* __restrict__ w,
                          const int* __restrict__ mode,
                          const float* __restrict__ dinv, int* cursor,
                          int* esrc, float* enorm, int E, int Nn) {
    int e = blockIdx.x * blockDim.x + threadIdx.x;
    if (e >= E) return;
    int m64 = mode[0];
    int s = ld_src(ei, e, E, m64);
    int d = ld_dst(ei, e, E, m64);
    if ((unsigned)s < (unsigned)Nn && (unsigned)d < (unsigned)Nn) {
        int pos = atomicAdd(cursor + d, 1);
        esrc[pos] = s;
        enorm[pos] = dinv[s] * w[e] * dinv[d];
    }
}

// ---------------- aggregation 1: ax = A_norm @ x  (bf16 in/out, fp32 acc) ----------------

__global__ __launch_bounds__(256) void k_agg1(const ushort_t* __restrict__ xb,
                                              const int* __restrict__ offs,
                                              const int* __restrict__ esrc,
                                              const float* __restrict__ enorm,
                                              const float* __restrict__ dinv,
                                              ushort_t* __restrict__ ax, int Nn) {
    int v = (blockIdx.x * blockDim.x + threadIdx.x) >> 6;
    int lane = threadIdx.x & 63;
    if (v >= Nn) return;
    float dv = dinv[v];
    float sn = dv * dv;  // self-loop norm
    ushort2 p = ((const ushort2*)(xb + (size_t)v * 128))[lane];
    float a0 = b2f(p.x) * sn, a1 = b2f(p.y) * sn;
    int s = offs[v], e = offs[v + 1];
    for (int i = s; i < e; ++i) {
        int u = esrc[i];
        if ((unsigned)u >= (unsigned)Nn) continue;
        float nw = enorm[i];
        ushort2 q = ((const ushort2*)(xb + (size_t)u * 128))[lane];
        a0 += b2f(q.x) * nw;
        a1 += b2f(q.y) * nw;
    }
    ushort2 o; o.x = f2b(a0); o.y = f2b(a1);
    ((ushort2*)(ax + (size_t)v * 128))[lane] = o;
}

// ---------------- fused GEMM: h2 = relu(ax @ W1^T + b1) @ W2^T ----------------
// MFMA 16x16x32 bf16. A frag: row=lane&15, k=quad*8+j. B frag: col=lane&15,
// k=quad*8+j. D: col=lane&15, row=quad*4+reg. ReLU'd 16x256 tile through LDS
// (row stride 264 ushorts = 528 B: 16 B aligned, 2-way banks = free).

__global__ __launch_bounds__(256) void k_gemm_fused(const ushort_t* __restrict__ ax,
                                                    const ushort_t* __restrict__ W1b,
                                                    const float* __restrict__ b1v,
                                                    const ushort_t* __restrict__ W2b,
                                                    ushort_t* __restrict__ h2, int Nn) {
    __shared__ ushort_t tile[4][16][264];
    int tid = threadIdx.x, wid = tid >> 6, lane = tid & 63;
    int m = lane & 15, q = lane >> 4;
    int arow = blockIdx.x * 64 + wid * 16 + m;
    bool rvalid = arow < Nn;
    const ushort_t* aptr = ax + (size_t)arow * 128 + q * 8;
    const ushort_t* w1base = W1b + (size_t)m * 128 + q * 8;

    float4v acc[16];
#pragma unroll
    for (int i = 0; i < 16; ++i) acc[i] = (float4v){0.f, 0.f, 0.f, 0.f};

#pragma unroll
    for (int kt = 0; kt < 4; ++kt) {
        short8 af = rvalid ? *(const short8*)(aptr + kt * 32) : (short8)0;
#pragma unroll
        for (int nt = 0; nt < 16; ++nt) {
            short8 bf = *(const short8*)(w1base + (size_t)nt * 16 * 128 + kt * 32);
            acc[nt] = __builtin_amdgcn_mfma_f32_16x16x32_bf16(af, bf, acc[nt], 0, 0, 0);
        }
    }

    // epilogue 1: bias + ReLU -> LDS (bf16)
#pragma unroll
    for (int nt = 0; nt < 16; ++nt) {
        int col = nt * 16 + m;
        float bb = b1v[col];
#pragma unroll
        for (int r = 0; r < 4; ++r) {
            float v = acc[nt][r] + bb;
            v = v > 0.f ? v : 0.f;
            tile[wid][q * 4 + r][col] = f2b(v);
        }
    }
    __syncthreads();

    // GEMM2 from LDS tile
    const ushort_t* w2base = W2b + (size_t)m * 256 + q * 8;
    float4v acc2[8];
#pragma unroll
    for (int i = 0; i < 8; ++i) acc2[i] = (float4v){0.f, 0.f, 0.f, 0.f};

#pragma unroll
    for (int kt = 0; kt < 8; ++kt) {
        short8 af2 = *(const short8*)&tile[wid][m][kt * 32 + q * 8];
#pragma unroll
        for (int nt = 0; nt < 8; ++nt) {
            short8 bf = *(const short8*)(w2base + (size_t)nt * 16 * 256 + kt * 32);
            acc2[nt] = __builtin_amdgcn_mfma_f32_16x16x32_bf16(af2, bf, acc2[nt], 0, 0, 0);
        }
    }

    int orow0 = blockIdx.x * 64 + wid * 16 + q * 4;
#pragma unroll
    for (int nt = 0; nt < 8; ++nt) {
        int col = nt * 16 + m;
#pragma unroll
        for (int r = 0; r < 4; ++r) {
            int row = orow0 + r;
            if (row < Nn) h2[(size_t)row * 128 + col] = f2b(acc2[nt][r]);
        }
    }
}

// ---------------- aggregation 2 + bias + LayerNorm (fp32 out) ----------------

__global__ __launch_bounds__(256) void k_agg2_ln(const ushort_t* __restrict__ h2,
                                                 const int* __restrict__ offs,
                                                 const int* __restrict__ esrc,
                                                 const float* __restrict__ enorm,
                                                 const float* __restrict__ dinv,
                                                 const float* __restrict__ b2v,
                                                 const float* __restrict__ gv,
                                                 const float* __restrict__ bev,
                                                 float* __restrict__ out, int Nn) {
    int v = (blockIdx.x * blockDim.x + threadIdx.x) >> 6;
    int lane = threadIdx.x & 63;
    if (v >= Nn) return;
    float dv = dinv[v];
    float sn = dv * dv;
    ushort2 p = ((const ushort2*)(h2 + (size_t)v * 128))[lane];
    float a0 = b2f(p.x) * sn, a1 = b2f(p.y) * sn;
    int s = offs[v], e = offs[v + 1];
    for (int i = s; i < e; ++i) {
        int u = esrc[i];
        if ((unsigned)u >= (unsigned)Nn) continue;
        float nw = enorm[i];
        ushort2 q = ((const ushort2*)(h2 + (size_t)u * 128))[lane];
        a0 += b2f(q.x) * nw;
        a1 += b2f(q.y) * nw;
    }
    int d0 = lane * 2;
    a0 += b2v[d0];
    a1 += b2v[d0 + 1];
    float ssum = a0 + a1, ssq = a0 * a0 + a1 * a1;
#pragma unroll
    for (int off = 1; off < 64; off <<= 1) {
        ssum += __shfl_xor(ssum, off);
        ssq += __shfl_xor(ssq, off);
    }
    float mu = ssum * (1.0f / 128.0f);
    float var = ssq * (1.0f / 128.0f) - mu * mu;
    float r = rsqrtf(var + 1e-5f);
    float2 o;
    o.x = (a0 - mu) * r * gv[d0] + bev[d0];
    o.y = (a1 - mu) * r * gv[d0 + 1] + bev[d0 + 1];
    ((float2*)(out + (size_t)v * 128))[lane] = o;
}

// ---------------- launch ----------------

extern "C" void kernel_launch(void* const* d_in, const int* in_sizes, int n_in,
                              void* d_out, int out_size, void* d_ws, size_t ws_size,
                              hipStream_t stream) {
    const float* x   = (const float*)d_in[0];  // [N,128] f32
    const int*   ei  = (const int*)d_in[1];    // [2,E] int32 (or int64 -> detected)
    const float* ew  = (const float*)d_in[2];  // [E] f32
    const float* W1  = (const float*)d_in[3];  // [256,128] f32
    const float* b1v = (const float*)d_in[4];  // [256]
    const float* W2  = (const float*)d_in[5];  // [128,256]
    const float* b2v = (const float*)d_in[6];  // [128]
    const float* gv  = (const float*)d_in[7];  // [128]
    const float* bev = (const float*)d_in[8];  // [128]
    float* out = (float*)d_out;

    const int Nn = in_sizes[0] / 128;
    const int E  = in_sizes[2];

    // workspace ~33 MB
    char* base = (char*)d_ws;
    size_t off = 0;
    auto alloc = [&](size_t bytes) {
        char* p = base + off;
        off = (off + bytes + 255) & ~(size_t)255;
        return p;
    };
    int*   mode   = (int*)alloc(4);
    float* degf   = (float*)alloc((size_t)Nn * 4);
    int*   cnt    = (int*)alloc((size_t)Nn * 4);
    int*   offs   = (int*)alloc((size_t)(Nn + 1) * 4);
    int*   cursor = (int*)alloc((size_t)Nn * 4);
    int*   esrc   = (int*)alloc((size_t)E * 4);
    float* enorm  = (float*)alloc((size_t)E * 4);
    ushort_t* xb  = (ushort_t*)alloc((size_t)Nn * 128 * 2);
    ushort_t* h2  = (ushort_t*)alloc((size_t)Nn * 128 * 2);
    ushort_t* W1b = (ushort_t*)alloc(32768 * 2);
    ushort_t* W2b = (ushort_t*)alloc(32768 * 2);
    ushort_t* ax  = (ushort_t*)d_out;  // stage ax in d_out (bf16, 12.8MB of 25.6MB); dead before final write
    (void)ws_size; (void)n_in; (void)out_size;

    int gN = (Nn + 255) / 256;
    int gE = (E + 255) / 256;
    int gW = (Nn + 3) / 4;        // wave per node
    int gG = (Nn + 63) / 64;      // 64 rows per block
    int n4 = Nn * 128 / 4;

    k_mode<<<1, 256, 0, stream>>>(ei, E, mode);
    k_node_init<<<gN, 256, 0, stream>>>(degf, cnt, Nn);
    k_count<<<gE, 256, 0, stream>>>(ei, ew, mode, degf, cnt, E, Nn);
    k_scan<<<1, 1024, 0, stream>>>(cnt, offs, cursor, Nn);
    k_dinv<<<gN, 256, 0, stream>>>(degf, Nn);
    k_scatter<<<gE, 256, 0, stream>>>(ei, ew, mode, degf, cursor, esrc, enorm, E, Nn);
    k_cast_x<<<(n4 + 255) / 256, 256, 0, stream>>>(x, xb, n4);
    k_cast_w<<<256, 256, 0, stream>>>(W1, W2, W1b, W2b);
    k_agg1<<<gW, 256, 0, stream>>>(xb, offs, esrc, enorm, degf, ax, Nn);
    k_gemm_fused<<<gG, 256, 0, stream>>>(ax, W1b, b1v, W2b, h2, Nn);
    k_agg2_ln<<<gW, 256, 0, stream>>>(h2, offs, esrc, enorm, degf, b2v, gv, bev, out, Nn);
}

// Round 4
// 377.795 us; speedup vs baseline: 1.4941x; 1.4941x over previous
//
#include <hip/hip_runtime.h>

typedef unsigned short ushort_t;
typedef __attribute__((ext_vector_type(8))) short short8;
typedef __attribute__((ext_vector_type(4))) float float4v;

__device__ inline float b2f(ushort_t u) {
    unsigned x = ((unsigned)u) << 16;
    return __builtin_bit_cast(float, x);
}
__device__ inline ushort_t f2b(float f) {
    unsigned x = __builtin_bit_cast(unsigned, f);
    unsigned r = (x + 0x7fffu + ((x >> 16) & 1u)) >> 16;
    return (ushort_t)r;
}

// ---------------- int64-vs-int32 edge_index layout detection ----------------

__global__ void k_mode(const int* __restrict__ ei, int E, int* mode) {
    __shared__ int any32;
    if (threadIdx.x == 0) any32 = 0;
    __syncthreads();
    for (int i = threadIdx.x; i < 1024; i += blockDim.x) {
        int slot = 2 * i + 1;
        if (slot < 2 * E && ei[slot] != 0) atomicOr(&any32, 1);
    }
    __syncthreads();
    if (threadIdx.x == 0) mode[0] = any32 ? 0 : 1;  // 1 => int64 layout
}

__device__ inline int ld_src(const int* __restrict__ ei, int e, int E, int m64) {
    return m64 ? ei[2 * (size_t)e] : ei[e];
}
__device__ inline int ld_dst(const int* __restrict__ ei, int e, int E, int m64) {
    return m64 ? ei[2 * ((size_t)E + e)] : ei[(size_t)E + e];
}

// ---------------- fp32 -> bf16 casts ----------------

__global__ void k_cast_x(const float* __restrict__ x, ushort_t* __restrict__ xb, int n4) {
    int i = blockIdx.x * blockDim.x + threadIdx.x;
    if (i >= n4) return;
    float4v v = ((const float4v*)x)[i];
    ushort4 o;
    o.x = f2b(v[0]); o.y = f2b(v[1]); o.z = f2b(v[2]); o.w = f2b(v[3]);
    ((ushort4*)xb)[i] = o;
}

__global__ void k_cast_w(const float* __restrict__ W1, const float* __restrict__ W2,
                         ushort_t* __restrict__ W1b, ushort_t* __restrict__ W2b) {
    int i = blockIdx.x * blockDim.x + threadIdx.x;  // 0..65535
    if (i < 32768) W1b[i] = f2b(W1[i]);
    else W2b[i - 32768] = f2b(W2[i - 32768]);
}

// ---------------- degree/CSR build ----------------

__global__ void k_node_init(float* degf, int* cnt, int Nn) {
    int i = blockIdx.x * blockDim.x + threadIdx.x;
    if (i < Nn) { degf[i] = 1.0f; cnt[i] = 0; }  // self-loop weight 1
}

__global__ void k_count(const int* __restrict__ ei, const float* __restrict__ w,
                        const int* __restrict__ mode,
                        float* degf, int* cnt, int E, int Nn) {
    int e = blockIdx.x * blockDim.x + threadIdx.x;
    if (e >= E) return;
    int m64 = mode[0];
    int s = ld_src(ei, e, E, m64);
    int d = ld_dst(ei, e, E, m64);
    if ((unsigned)s < (unsigned)Nn && (unsigned)d < (unsigned)Nn) {
        atomicAdd(cnt + d, 1);
        atomicAdd(degf + d, w[e]);
    }
}

// ---------------- 3-phase multi-block exclusive scan (2048 elems/block) ----------------

__global__ __launch_bounds__(256) void k_scan_a(const int* __restrict__ cnt,
                                                int* __restrict__ bsum, int Nn) {
    int b = blockIdx.x, t = threadIdx.x;
    int base = b * 2048 + t * 8;
    int s = 0;
#pragma unroll
    for (int j = 0; j < 8; ++j) { int i = base + j; if (i < Nn) s += cnt[i]; }
#pragma unroll
    for (int off = 1; off < 64; off <<= 1) s += __shfl_xor(s, off);
    __shared__ int wsum[4];
    if ((t & 63) == 0) wsum[t >> 6] = s;
    __syncthreads();
    if (t == 0) bsum[b] = wsum[0] + wsum[1] + wsum[2] + wsum[3];
}

// nb <= 64 (2048*64 = 131072 max elems). One wave.
__global__ void k_scan_b(const int* __restrict__ bsum, int* __restrict__ bbase,
                         int nb, int* __restrict__ offs, int Nn) {
    int t = threadIdx.x;
    int own = (t < nb) ? bsum[t] : 0;
    int v = own;
#pragma unroll
    for (int off = 1; off < 64; off <<= 1) {
        int u = __shfl_up(v, off);
        if (t >= off) v += u;
    }
    if (t < nb) bbase[t] = v - own;  // exclusive
    if (t == 63) offs[Nn] = v;       // grand total
}

__global__ __launch_bounds__(256) void k_scan_c(const int* __restrict__ cnt,
                                                const int* __restrict__ bbase,
                                                int* __restrict__ offs,
                                                int* __restrict__ cursor, int Nn) {
    int b = blockIdx.x, t = threadIdx.x;
    int base = b * 2048 + t * 8;
    int v[8];
    int s = 0;
#pragma unroll
    for (int j = 0; j < 8; ++j) {
        int i = base + j;
        v[j] = (i < Nn) ? cnt[i] : 0;
        s += v[j];
    }
    __shared__ int sd[256];
    sd[t] = s;
    __syncthreads();
    for (int off = 1; off < 256; off <<= 1) {
        int u = (t >= off) ? sd[t - off] : 0;
        __syncthreads();
        sd[t] += u;
        __syncthreads();
    }
    int pos = bbase[b] + sd[t] - s;  // block base + thread-exclusive
#pragma unroll
    for (int j = 0; j < 8; ++j) {
        int i = base + j;
        if (i < Nn) { offs[i] = pos; cursor[i] = pos; pos += v[j]; }
    }
}

__global__ void k_dinv(float* degf, int Nn) {
    int i = blockIdx.x * blockDim.x + threadIdx.x;
    if (i < Nn) degf[i] = rsqrtf(degf[i]);  // deg >= 1 (self loop)
}

__global__ void k_scatter(const int* __restrict__ ei, const float* __restrict__ w,
                          const int* __restrict__ mode,
                          const float* __restrict__ dinv, int* cursor,
                          int* esrc, float* enorm, int E, int Nn) {
    int e = blockIdx.x * blockDim.x + threadIdx.x;
    if (e >= E) return;
    int m64 = mode[0];
    int s = ld_src(ei, e, E, m64);
    int d = ld_dst(ei, e, E, m64);
    if ((unsigned)s < (unsigned)Nn && (unsigned)d < (unsigned)Nn) {
        int pos = atomicAdd(cursor + d, 1);
        esrc[pos] = s;
        enorm[pos] = dinv[s] * w[e] * dinv[d];
    }
}

// ---------------- aggregation 1: ax = A_norm @ x  (bf16 in/out, fp32 acc) ----------------
// wave per node; 4x unrolled edge loop for MLP.

__global__ __launch_bounds__(256) void k_agg1(const ushort_t* __restrict__ xb,
                                              const int* __restrict__ offs,
                                              const int* __restrict__ esrc,
                                              const float* __restrict__ enorm,
                                              const float* __restrict__ dinv,
                                              ushort_t* __restrict__ ax, int Nn) {
    int v = (blockIdx.x * blockDim.x + threadIdx.x) >> 6;
    int lane = threadIdx.x & 63;
    if (v >= Nn) return;
    float dv = dinv[v];
    float sn = dv * dv;  // self-loop norm
    ushort2 p = ((const ushort2*)(xb + (size_t)v * 128))[lane];
    float a0 = b2f(p.x) * sn, a1 = b2f(p.y) * sn;
    int s = offs[v], e = offs[v + 1];
    int i = s;
    for (; i + 3 < e; i += 4) {
        int u0 = esrc[i], u1 = esrc[i + 1], u2 = esrc[i + 2], u3 = esrc[i + 3];
        float n0 = enorm[i], n1 = enorm[i + 1], n2 = enorm[i + 2], n3 = enorm[i + 3];
        ushort2 q0 = ((const ushort2*)(xb + (size_t)u0 * 128))[lane];
        ushort2 q1 = ((const ushort2*)(xb + (size_t)u1 * 128))[lane];
        ushort2 q2 = ((const ushort2*)(xb + (size_t)u2 * 128))[lane];
        ushort2 q3 = ((const ushort2*)(xb + (size_t)u3 * 128))[lane];
        a0 += b2f(q0.x) * n0; a1 += b2f(q0.y) * n0;
        a0 += b2f(q1.x) * n1; a1 += b2f(q1.y) * n1;
        a0 += b2f(q2.x) * n2; a1 += b2f(q2.y) * n2;
        a0 += b2f(q3.x) * n3; a1 += b2f(q3.y) * n3;
    }
    for (; i < e; ++i) {
        int u = esrc[i];
        float nw = enorm[i];
        ushort2 q = ((const ushort2*)(xb + (size_t)u * 128))[lane];
        a0 += b2f(q.x) * nw;
        a1 += b2f(q.y) * nw;
    }
    ushort2 o; o.x = f2b(a0); o.y = f2b(a1);
    ((ushort2*)(ax + (size_t)v * 128))[lane] = o;
}

// ---------------- fused GEMM: h2 = relu(ax @ W1^T + b1) @ W2^T ----------------
// MFMA 16x16x32 bf16. A frag: row=lane&15, k=quad*8+j. B frag: col=lane&15,
// k=quad*8+j. D: col=lane&15, row=quad*4+reg. ReLU'd 16x256 tile through LDS
// (row stride 264 ushorts = 528 B: 16 B aligned, 2-way banks = free).

__global__ __launch_bounds__(256) void k_gemm_fused(const ushort_t* __restrict__ ax,
                                                    const ushort_t* __restrict__ W1b,
                                                    const float* __restrict__ b1v,
                                                    const ushort_t* __restrict__ W2b,
                                                    ushort_t* __restrict__ h2, int Nn) {
    __shared__ ushort_t tile[4][16][264];
    int tid = threadIdx.x, wid = tid >> 6, lane = tid & 63;
    int m = lane & 15, q = lane >> 4;
    int arow = blockIdx.x * 64 + wid * 16 + m;
    bool rvalid = arow < Nn;
    const ushort_t* aptr = ax + (size_t)arow * 128 + q * 8;
    const ushort_t* w1base = W1b + (size_t)m * 128 + q * 8;

    float4v acc[16];
#pragma unroll
    for (int i = 0; i < 16; ++i) acc[i] = (float4v){0.f, 0.f, 0.f, 0.f};

#pragma unroll
    for (int kt = 0; kt < 4; ++kt) {
        short8 af = rvalid ? *(const short8*)(aptr + kt * 32) : (short8)0;
#pragma unroll
        for (int nt = 0; nt < 16; ++nt) {
            short8 bf = *(const short8*)(w1base + (size_t)nt * 16 * 128 + kt * 32);
            acc[nt] = __builtin_amdgcn_mfma_f32_16x16x32_bf16(af, bf, acc[nt], 0, 0, 0);
        }
    }

#pragma unroll
    for (int nt = 0; nt < 16; ++nt) {
        int col = nt * 16 + m;
        float bb = b1v[col];
#pragma unroll
        for (int r = 0; r < 4; ++r) {
            float v = acc[nt][r] + bb;
            v = v > 0.f ? v : 0.f;
            tile[wid][q * 4 + r][col] = f2b(v);
        }
    }
    __syncthreads();

    const ushort_t* w2base = W2b + (size_t)m * 256 + q * 8;
    float4v acc2[8];
#pragma unroll
    for (int i = 0; i < 8; ++i) acc2[i] = (float4v){0.f, 0.f, 0.f, 0.f};

#pragma unroll
    for (int kt = 0; kt < 8; ++kt) {
        short8 af2 = *(const short8*)&tile[wid][m][kt * 32 + q * 8];
#pragma unroll
        for (int nt = 0; nt < 8; ++nt) {
            short8 bf = *(const short8*)(w2base + (size_t)nt * 16 * 256 + kt * 32);
            acc2[nt] = __builtin_amdgcn_mfma_f32_16x16x32_bf16(af2, bf, acc2[nt], 0, 0, 0);
        }
    }

    int orow0 = blockIdx.x * 64 + wid * 16 + q * 4;
#pragma unroll
    for (int nt = 0; nt < 8; ++nt) {
        int col = nt * 16 + m;
#pragma unroll
        for (int r = 0; r < 4; ++r) {
            int row = orow0 + r;
            if (row < Nn) h2[(size_t)row * 128 + col] = f2b(acc2[nt][r]);
        }
    }
}

// ---------------- aggregation 2 + bias + LayerNorm (fp32 out) ----------------

__global__ __launch_bounds__(256) void k_agg2_ln(const ushort_t* __restrict__ h2,
                                                 const int* __restrict__ offs,
                                                 const int* __restrict__ esrc,
                                                 const float* __restrict__ enorm,
                                                 const float* __restrict__ dinv,
                                                 const float* __restrict__ b2v,
                                                 const float* __restrict__ gv,
                                                 const float* __restrict__ bev,
                                                 float* __restrict__ out, int Nn) {
    int v = (blockIdx.x * blockDim.x + threadIdx.x) >> 6;
    int lane = threadIdx.x & 63;
    if (v >= Nn) return;
    float dv = dinv[v];
    float sn = dv * dv;
    ushort2 p = ((const ushort2*)(h2 + (size_t)v * 128))[lane];
    float a0 = b2f(p.x) * sn, a1 = b2f(p.y) * sn;
    int s = offs[v], e = offs[v + 1];
    int i = s;
    for (; i + 3 < e; i += 4) {
        int u0 = esrc[i], u1 = esrc[i + 1], u2 = esrc[i + 2], u3 = esrc[i + 3];
        float n0 = enorm[i], n1 = enorm[i + 1], n2 = enorm[i + 2], n3 = enorm[i + 3];
        ushort2 q0 = ((const ushort2*)(h2 + (size_t)u0 * 128))[lane];
        ushort2 q1 = ((const ushort2*)(h2 + (size_t)u1 * 128))[lane];
        ushort2 q2 = ((const ushort2*)(h2 + (size_t)u2 * 128))[lane];
        ushort2 q3 = ((const ushort2*)(h2 + (size_t)u3 * 128))[lane];
        a0 += b2f(q0.x) * n0; a1 += b2f(q0.y) * n0;
        a0 += b2f(q1.x) * n1; a1 += b2f(q1.y) * n1;
        a0 += b2f(q2.x) * n2; a1 += b2f(q2.y) * n2;
        a0 += b2f(q3.x) * n3; a1 += b2f(q3.y) * n3;
    }
    for (; i < e; ++i) {
        int u = esrc[i];
        float nw = enorm[i];
        ushort2 q = ((const ushort2*)(h2 + (size_t)u * 128))[lane];
        a0 += b2f(q.x) * nw;
        a1 += b2f(q.y) * nw;
    }
    int d0 = lane * 2;
    a0 += b2v[d0];
    a1 += b2v[d0 + 1];
    float ssum = a0 + a1, ssq = a0 * a0 + a1 * a1;
#pragma unroll
    for (int off = 1; off < 64; off <<= 1) {
        ssum += __shfl_xor(ssum, off);
        ssq += __shfl_xor(ssq, off);
    }
    float mu = ssum * (1.0f / 128.0f);
    float var = ssq * (1.0f / 128.0f) - mu * mu;
    float r = rsqrtf(var + 1e-5f);
    float2 o;
    o.x = (a0 - mu) * r * gv[d0] + bev[d0];
    o.y = (a1 - mu) * r * gv[d0 + 1] + bev[d0 + 1];
    ((float2*)(out + (size_t)v * 128))[lane] = o;
}

// ---------------- launch ----------------

extern "C" void kernel_launch(void* const* d_in, const int* in_sizes, int n_in,
                              void* d_out, int out_size, void* d_ws, size_t ws_size,
                              hipStream_t stream) {
    const float* x   = (const float*)d_in[0];  // [N,128] f32
    const int*   ei  = (const int*)d_in[1];    // [2,E] int32/int64 (detected)
    const float* ew  = (const float*)d_in[2];  // [E] f32
    const float* W1  = (const float*)d_in[3];  // [256,128] f32
    const float* b1v = (const float*)d_in[4];  // [256]
    const float* W2  = (const float*)d_in[5];  // [128,256]
    const float* b2v = (const float*)d_in[6];  // [128]
    const float* gv  = (const float*)d_in[7];  // [128]
    const float* bev = (const float*)d_in[8];  // [128]
    float* out = (float*)d_out;

    const int Nn = in_sizes[0] / 128;
    const int E  = in_sizes[2];

    char* base = (char*)d_ws;
    size_t off = 0;
    auto alloc = [&](size_t bytes) {
        char* p = base + off;
        off = (off + bytes + 255) & ~(size_t)255;
        return p;
    };
    int*   mode   = (int*)alloc(4);
    float* degf   = (float*)alloc((size_t)Nn * 4);
    int*   cnt    = (int*)alloc((size_t)Nn * 4);
    int*   offs   = (int*)alloc((size_t)(Nn + 1) * 4);
    int*   cursor = (int*)alloc((size_t)Nn * 4);
    int*   bsum   = (int*)alloc(64 * 4);
    int*   bbase  = (int*)alloc(64 * 4);
    int*   esrc   = (int*)alloc((size_t)E * 4);
    float* enorm  = (float*)alloc((size_t)E * 4);
    ushort_t* xb  = (ushort_t*)alloc((size_t)Nn * 128 * 2);
    ushort_t* h2  = (ushort_t*)alloc((size_t)Nn * 128 * 2);
    ushort_t* W1b = (ushort_t*)alloc(32768 * 2);
    ushort_t* W2b = (ushort_t*)alloc(32768 * 2);
    ushort_t* ax  = (ushort_t*)d_out;  // stage ax in d_out; dead before final write
    (void)ws_size; (void)n_in; (void)out_size;

    int gN = (Nn + 255) / 256;
    int gE = (E + 255) / 256;
    int gW = (Nn + 3) / 4;        // wave per node
    int gG = (Nn + 63) / 64;      // 64 rows per block
    int n4 = Nn * 128 / 4;
    int nb = (Nn + 2047) / 2048;  // scan blocks (<= 64)

    k_mode<<<1, 256, 0, stream>>>(ei, E, mode);
    k_node_init<<<gN, 256, 0, stream>>>(degf, cnt, Nn);
    k_count<<<gE, 256, 0, stream>>>(ei, ew, mode, degf, cnt, E, Nn);
    k_scan_a<<<nb, 256, 0, stream>>>(cnt, bsum, Nn);
    k_scan_b<<<1, 64, 0, stream>>>(bsum, bbase, nb, offs, Nn);
    k_scan_c<<<nb, 256, 0, stream>>>(cnt, bbase, offs, cursor, Nn);
    k_dinv<<<gN, 256, 0, stream>>>(degf, Nn);
    k_scatter<<<gE, 256, 0, stream>>>(ei, ew, mode, degf, cursor, esrc, enorm, E, Nn);
    k_cast_x<<<(n4 + 255) / 256, 256, 0, stream>>>(x, xb, n4);
    k_cast_w<<<256, 256, 0, stream>>>(W1, W2, W1b, W2b);
    k_agg1<<<gW, 256, 0, stream>>>(xb, offs, esrc, enorm, degf, ax, Nn);
    k_gemm_fused<<<gG, 256, 0, stream>>>(ax, W1b, b1v, W2b, h2, Nn);
    k_agg2_ln<<<gW, 256, 0, stream>>>(h2, offs, esrc, enorm, degf, b2v, gv, bev, out, Nn);
}

// Round 5
// 316.311 us; speedup vs baseline: 1.7845x; 1.1944x over previous
//
#include <hip/hip_runtime.h>

typedef unsigned short ushort_t;
typedef unsigned long long u64_t;
typedef __attribute__((ext_vector_type(8))) short short8;
typedef __attribute__((ext_vector_type(4))) float float4v;

__device__ inline float b2f(ushort_t u) {
    unsigned x = ((unsigned)u) << 16;
    return __builtin_bit_cast(float, x);
}
__device__ inline ushort_t f2b(float f) {
    unsigned x = __builtin_bit_cast(unsigned, f);
    unsigned r = (x + 0x7fffu + ((x >> 16) & 1u)) >> 16;
    return (ushort_t)r;
}

// ---------------- int64-vs-int32 edge_index layout detection ----------------

__global__ void k_mode(const int* __restrict__ ei, int E, int* mode) {
    __shared__ int any32;
    if (threadIdx.x == 0) any32 = 0;
    __syncthreads();
    for (int i = threadIdx.x; i < 1024; i += blockDim.x) {
        int slot = 2 * i + 1;
        if (slot < 2 * E && ei[slot] != 0) atomicOr(&any32, 1);
    }
    __syncthreads();
    if (threadIdx.x == 0) mode[0] = any32 ? 0 : 1;  // 1 => int64 layout
}

__device__ inline int ld_src(const int* __restrict__ ei, int e, int E, int m64) {
    return m64 ? ei[2 * (size_t)e] : ei[e];
}
__device__ inline int ld_dst(const int* __restrict__ ei, int e, int E, int m64) {
    return m64 ? ei[2 * ((size_t)E + e)] : ei[(size_t)E + e];
}

// ---------------- fp32 -> bf16 casts ----------------

__global__ void k_cast_x(const float* __restrict__ x, ushort_t* __restrict__ xb, int n4) {
    int i = blockIdx.x * blockDim.x + threadIdx.x;
    if (i >= n4) return;
    float4v v = ((const float4v*)x)[i];
    ushort4 o;
    o.x = f2b(v[0]); o.y = f2b(v[1]); o.z = f2b(v[2]); o.w = f2b(v[3]);
    ((ushort4*)xb)[i] = o;
}

__global__ void k_cast_w(const float* __restrict__ W1, const float* __restrict__ W2,
                         ushort_t* __restrict__ W1b, ushort_t* __restrict__ W2b) {
    int i = blockIdx.x * blockDim.x + threadIdx.x;  // 0..65535
    if (i < 32768) W1b[i] = f2b(W1[i]);
    else W2b[i - 32768] = f2b(W2[i - 32768]);
}

// ---------------- degree/CSR build ----------------
// packed[d]: high 32 = edge count, low 32 = sum(w) in 8.24 fixed point.
// One 64-bit atomic per edge; returned old high word = within-segment rank.

__global__ void k_node_init(u64_t* packed, int Nn) {
    int i = blockIdx.x * blockDim.x + threadIdx.x;
    if (i < Nn) packed[i] = 0ull;
}

__global__ void k_count(const int* __restrict__ ei, const float* __restrict__ w,
                        const int* __restrict__ mode,
                        u64_t* packed, int* __restrict__ rank, int E, int Nn) {
    int e = blockIdx.x * blockDim.x + threadIdx.x;
    if (e >= E) return;
    int m64 = mode[0];
    int s = ld_src(ei, e, E, m64);
    int d = ld_dst(ei, e, E, m64);
    if ((unsigned)s < (unsigned)Nn && (unsigned)d < (unsigned)Nn) {
        unsigned fx = (unsigned)(w[e] * 16777216.0f + 0.5f);
        u64_t old = atomicAdd(packed + d, (1ull << 32) | (u64_t)fx);
        rank[e] = (int)(old >> 32);
    } else {
        rank[e] = -1;
    }
}

__device__ inline int cnt_hi(const u64_t* packed, int i) {
    return ((const int*)packed)[2 * i + 1];  // little-endian high word
}

// ---------------- 3-phase multi-block exclusive scan over cnt_hi ----------------

__global__ __launch_bounds__(256) void k_scan_a(const u64_t* __restrict__ packed,
                                                int* __restrict__ bsum, int Nn) {
    int b = blockIdx.x, t = threadIdx.x;
    int base = b * 2048 + t * 8;
    int s = 0;
#pragma unroll
    for (int j = 0; j < 8; ++j) { int i = base + j; if (i < Nn) s += cnt_hi(packed, i); }
#pragma unroll
    for (int off = 1; off < 64; off <<= 1) s += __shfl_xor(s, off);
    __shared__ int wsum[4];
    if ((t & 63) == 0) wsum[t >> 6] = s;
    __syncthreads();
    if (t == 0) bsum[b] = wsum[0] + wsum[1] + wsum[2] + wsum[3];
}

// nb <= 64. One wave.
__global__ void k_scan_b(const int* __restrict__ bsum, int* __restrict__ bbase,
                         int nb, int* __restrict__ offs, int Nn) {
    int t = threadIdx.x;
    int own = (t < nb) ? bsum[t] : 0;
    int v = own;
#pragma unroll
    for (int off = 1; off < 64; off <<= 1) {
        int u = __shfl_up(v, off);
        if (t >= off) v += u;
    }
    if (t < nb) bbase[t] = v - own;  // exclusive
    if (t == 63) offs[Nn] = v;       // grand total
}

__global__ __launch_bounds__(256) void k_scan_c(const u64_t* __restrict__ packed,
                                                const int* __restrict__ bbase,
                                                int* __restrict__ offs, int Nn) {
    int b = blockIdx.x, t = threadIdx.x;
    int base = b * 2048 + t * 8;
    int v[8];
    int s = 0;
#pragma unroll
    for (int j = 0; j < 8; ++j) {
        int i = base + j;
        v[j] = (i < Nn) ? cnt_hi(packed, i) : 0;
        s += v[j];
    }
    __shared__ int sd[256];
    sd[t] = s;
    __syncthreads();
    for (int off = 1; off < 256; off <<= 1) {
        int u = (t >= off) ? sd[t - off] : 0;
        __syncthreads();
        sd[t] += u;
        __syncthreads();
    }
    int pos = bbase[b] + sd[t] - s;
#pragma unroll
    for (int j = 0; j < 8; ++j) {
        int i = base + j;
        if (i < Nn) { offs[i] = pos; pos += v[j]; }
    }
}

__global__ void k_dinv(const u64_t* __restrict__ packed, float* dinv, int Nn) {
    int i = blockIdx.x * blockDim.x + threadIdx.x;
    if (i >= Nn) return;
    float deg = 1.0f + (float)(unsigned)(packed[i] & 0xFFFFFFFFull) * (1.0f / 16777216.0f);
    dinv[i] = rsqrtf(deg);  // deg >= 1 (self loop)
}

// ---------------- scatter (atomic-free): edata[pos] = {src, bits(norm)} ----------------

__global__ void k_scatter(const int* __restrict__ ei, const float* __restrict__ w,
                          const int* __restrict__ mode,
                          const float* __restrict__ dinv,
                          const int* __restrict__ offs,
                          const int* __restrict__ rank,
                          int2* __restrict__ edata, int E, int Nn) {
    int e = blockIdx.x * blockDim.x + threadIdx.x;
    if (e >= E) return;
    int r = rank[e];
    if (r < 0) return;
    int m64 = mode[0];
    int s = ld_src(ei, e, E, m64);
    int d = ld_dst(ei, e, E, m64);
    int pos = offs[d] + r;
    float nw = dinv[s] * w[e] * dinv[d];
    int2 p;
    p.x = s;
    p.y = __builtin_bit_cast(int, nw);
    edata[pos] = p;
}

// ---------------- aggregation 1: ax = A_norm @ x  (bf16 in/out, fp32 acc) ----------------

__global__ __launch_bounds__(256) void k_agg1(const ushort_t* __restrict__ xb,
                                              const int* __restrict__ offs,
                                              const int2* __restrict__ edata,
                                              const float* __restrict__ dinv,
                                              ushort_t* __restrict__ ax, int Nn) {
    int v = (blockIdx.x * blockDim.x + threadIdx.x) >> 6;
    int lane = threadIdx.x & 63;
    if (v >= Nn) return;
    float dv = dinv[v];
    float sn = dv * dv;  // self-loop norm
    ushort2 p = ((const ushort2*)(xb + (size_t)v * 128))[lane];
    float a0 = b2f(p.x) * sn, a1 = b2f(p.y) * sn;
    int s = offs[v], e = offs[v + 1];
    int i = s;
    for (; i + 3 < e; i += 4) {
        int2 e0 = edata[i], e1 = edata[i + 1], e2 = edata[i + 2], e3 = edata[i + 3];
        float n0 = __builtin_bit_cast(float, e0.y);
        float n1 = __builtin_bit_cast(float, e1.y);
        float n2 = __builtin_bit_cast(float, e2.y);
        float n3 = __builtin_bit_cast(float, e3.y);
        ushort2 q0 = ((const ushort2*)(xb + (size_t)e0.x * 128))[lane];
        ushort2 q1 = ((const ushort2*)(xb + (size_t)e1.x * 128))[lane];
        ushort2 q2 = ((const ushort2*)(xb + (size_t)e2.x * 128))[lane];
        ushort2 q3 = ((const ushort2*)(xb + (size_t)e3.x * 128))[lane];
        a0 += b2f(q0.x) * n0; a1 += b2f(q0.y) * n0;
        a0 += b2f(q1.x) * n1; a1 += b2f(q1.y) * n1;
        a0 += b2f(q2.x) * n2; a1 += b2f(q2.y) * n2;
        a0 += b2f(q3.x) * n3; a1 += b2f(q3.y) * n3;
    }
    for (; i < e; ++i) {
        int2 ed = edata[i];
        float nw = __builtin_bit_cast(float, ed.y);
        ushort2 q = ((const ushort2*)(xb + (size_t)ed.x * 128))[lane];
        a0 += b2f(q.x) * nw;
        a1 += b2f(q.y) * nw;
    }
    ushort2 o; o.x = f2b(a0); o.y = f2b(a1);
    ((ushort2*)(ax + (size_t)v * 128))[lane] = o;
}

// ---------------- fused GEMM: h2 = relu(ax @ W1^T + b1) @ W2^T ----------------

__global__ __launch_bounds__(256) void k_gemm_fused(const ushort_t* __restrict__ ax,
                                                    const ushort_t* __restrict__ W1b,
                                                    const float* __restrict__ b1v,
                                                    const ushort_t* __restrict__ W2b,
                                                    ushort_t* __restrict__ h2, int Nn) {
    __shared__ ushort_t tile[4][16][264];
    int tid = threadIdx.x, wid = tid >> 6, lane = tid & 63;
    int m = lane & 15, q = lane >> 4;
    int arow = blockIdx.x * 64 + wid * 16 + m;
    bool rvalid = arow < Nn;
    const ushort_t* aptr = ax + (size_t)arow * 128 + q * 8;
    const ushort_t* w1base = W1b + (size_t)m * 128 + q * 8;

    float4v acc[16];
#pragma unroll
    for (int i = 0; i < 16; ++i) acc[i] = (float4v){0.f, 0.f, 0.f, 0.f};

#pragma unroll
    for (int kt = 0; kt < 4; ++kt) {
        short8 af = rvalid ? *(const short8*)(aptr + kt * 32) : (short8)0;
#pragma unroll
        for (int nt = 0; nt < 16; ++nt) {
            short8 bf = *(const short8*)(w1base + (size_t)nt * 16 * 128 + kt * 32);
            acc[nt] = __builtin_amdgcn_mfma_f32_16x16x32_bf16(af, bf, acc[nt], 0, 0, 0);
        }
    }

#pragma unroll
    for (int nt = 0; nt < 16; ++nt) {
        int col = nt * 16 + m;
        float bb = b1v[col];
#pragma unroll
        for (int r = 0; r < 4; ++r) {
            float v = acc[nt][r] + bb;
            v = v > 0.f ? v : 0.f;
            tile[wid][q * 4 + r][col] = f2b(v);
        }
    }
    __syncthreads();

    const ushort_t* w2base = W2b + (size_t)m * 256 + q * 8;
    float4v acc2[8];
#pragma unroll
    for (int i = 0; i < 8; ++i) acc2[i] = (float4v){0.f, 0.f, 0.f, 0.f};

#pragma unroll
    for (int kt = 0; kt < 8; ++kt) {
        short8 af2 = *(const short8*)&tile[wid][m][kt * 32 + q * 8];
#pragma unroll
        for (int nt = 0; nt < 8; ++nt) {
            short8 bf = *(const short8*)(w2base + (size_t)nt * 16 * 256 + kt * 32);
            acc2[nt] = __builtin_amdgcn_mfma_f32_16x16x32_bf16(af2, bf, acc2[nt], 0, 0, 0);
        }
    }

    int orow0 = blockIdx.x * 64 + wid * 16 + q * 4;
#pragma unroll
    for (int nt = 0; nt < 8; ++nt) {
        int col = nt * 16 + m;
#pragma unroll
        for (int r = 0; r < 4; ++r) {
            int row = orow0 + r;
            if (row < Nn) h2[(size_t)row * 128 + col] = f2b(acc2[nt][r]);
        }
    }
}

// ---------------- aggregation 2 + bias + LayerNorm (fp32 out) ----------------

__global__ __launch_bounds__(256) void k_agg2_ln(const ushort_t* __restrict__ h2,
                                                 const int* __restrict__ offs,
                                                 const int2* __restrict__ edata,
                                                 const float* __restrict__ dinv,
                                                 const float* __restrict__ b2v,
                                                 const float* __restrict__ gv,
                                                 const float* __restrict__ bev,
                                                 float* __restrict__ out, int Nn) {
    int v = (blockIdx.x * blockDim.x + threadIdx.x) >> 6;
    int lane = threadIdx.x & 63;
    if (v >= Nn) return;
    float dv = dinv[v];
    float sn = dv * dv;
    ushort2 p = ((const ushort2*)(h2 + (size_t)v * 128))[lane];
    float a0 = b2f(p.x) * sn, a1 = b2f(p.y) * sn;
    int s = offs[v], e = offs[v + 1];
    int i = s;
    for (; i + 3 < e; i += 4) {
        int2 e0 = edata[i], e1 = edata[i + 1], e2 = edata[i + 2], e3 = edata[i + 3];
        float n0 = __builtin_bit_cast(float, e0.y);
        float n1 = __builtin_bit_cast(float, e1.y);
        float n2 = __builtin_bit_cast(float, e2.y);
        float n3 = __builtin_bit_cast(float, e3.y);
        ushort2 q0 = ((const ushort2*)(h2 + (size_t)e0.x * 128))[lane];
        ushort2 q1 = ((const ushort2*)(h2 + (size_t)e1.x * 128))[lane];
        ushort2 q2 = ((const ushort2*)(h2 + (size_t)e2.x * 128))[lane];
        ushort2 q3 = ((const ushort2*)(h2 + (size_t)e3.x * 128))[lane];
        a0 += b2f(q0.x) * n0; a1 += b2f(q0.y) * n0;
        a0 += b2f(q1.x) * n1; a1 += b2f(q1.y) * n1;
        a0 += b2f(q2.x) * n2; a1 += b2f(q2.y) * n2;
        a0 += b2f(q3.x) * n3; a1 += b2f(q3.y) * n3;
    }
    for (; i < e; ++i) {
        int2 ed = edata[i];
        float nw = __builtin_bit_cast(float, ed.y);
        ushort2 q = ((const ushort2*)(h2 + (size_t)ed.x * 128))[lane];
        a0 += b2f(q.x) * nw;
        a1 += b2f(q.y) * nw;
    }
    int d0 = lane * 2;
    a0 += b2v[d0];
    a1 += b2v[d0 + 1];
    float ssum = a0 + a1, ssq = a0 * a0 + a1 * a1;
#pragma unroll
    for (int off = 1; off < 64; off <<= 1) {
        ssum += __shfl_xor(ssum, off);
        ssq += __shfl_xor(ssq, off);
    }
    float mu = ssum * (1.0f / 128.0f);
    float var = ssq * (1.0f / 128.0f) - mu * mu;
    float r = rsqrtf(var + 1e-5f);
    float2 o;
    o.x = (a0 - mu) * r * gv[d0] + bev[d0];
    o.y = (a1 - mu) * r * gv[d0 + 1] + bev[d0 + 1];
    ((float2*)(out + (size_t)v * 128))[lane] = o;
}

// ---------------- launch ----------------

extern "C" void kernel_launch(void* const* d_in, const int* in_sizes, int n_in,
                              void* d_out, int out_size, void* d_ws, size_t ws_size,
                              hipStream_t stream) {
    const float* x   = (const float*)d_in[0];  // [N,128] f32
    const int*   ei  = (const int*)d_in[1];    // [2,E] int32/int64 (detected)
    const float* ew  = (const float*)d_in[2];  // [E] f32
    const float* W1  = (const float*)d_in[3];  // [256,128] f32
    const float* b1v = (const float*)d_in[4];  // [256]
    const float* W2  = (const float*)d_in[5];  // [128,256]
    const float* b2v = (const float*)d_in[6];  // [128]
    const float* gv  = (const float*)d_in[7];  // [128]
    const float* bev = (const float*)d_in[8];  // [128]
    float* out = (float*)d_out;

    const int Nn = in_sizes[0] / 128;
    const int E  = in_sizes[2];

    char* base = (char*)d_ws;
    size_t off = 0;
    auto alloc = [&](size_t bytes) {
        char* p = base + off;
        off = (off + bytes + 255) & ~(size_t)255;
        return p;
    };
    int*    mode   = (int*)alloc(4);
    u64_t*  packed = (u64_t*)alloc((size_t)Nn * 8);
    float*  dinv   = (float*)alloc((size_t)Nn * 4);
    int*    offs   = (int*)alloc((size_t)(Nn + 1) * 4);
    int*    bsum   = (int*)alloc(64 * 4);
    int*    bbase  = (int*)alloc(64 * 4);
    int*    rank   = (int*)alloc((size_t)E * 4);
    int2*   edata  = (int2*)alloc((size_t)E * 8);
    ushort_t* xb   = (ushort_t*)alloc((size_t)Nn * 128 * 2);
    ushort_t* h2   = (ushort_t*)alloc((size_t)Nn * 128 * 2);
    ushort_t* W1b  = (ushort_t*)alloc(32768 * 2);
    ushort_t* W2b  = (ushort_t*)alloc(32768 * 2);
    ushort_t* ax   = (ushort_t*)d_out;  // stage ax in d_out; dead before final write
    (void)ws_size; (void)n_in; (void)out_size;

    int gN = (Nn + 255) / 256;
    int gE = (E + 255) / 256;
    int gW = (Nn + 3) / 4;        // wave per node
    int gG = (Nn + 63) / 64;      // 64 rows per block
    int n4 = Nn * 128 / 4;
    int nb = (Nn + 2047) / 2048;  // scan blocks (<= 64)

    k_mode<<<1, 256, 0, stream>>>(ei, E, mode);
    k_node_init<<<gN, 256, 0, stream>>>(packed, Nn);
    k_count<<<gE, 256, 0, stream>>>(ei, ew, mode, packed, rank, E, Nn);
    k_scan_a<<<nb, 256, 0, stream>>>(packed, bsum, Nn);
    k_scan_b<<<1, 64, 0, stream>>>(bsum, bbase, nb, offs, Nn);
    k_scan_c<<<nb, 256, 0, stream>>>(packed, bbase, offs, Nn);
    k_dinv<<<gN, 256, 0, stream>>>(packed, dinv, Nn);
    k_scatter<<<gE, 256, 0, stream>>>(ei, ew, mode, dinv, offs, rank, edata, E, Nn);
    k_cast_x<<<(n4 + 255) / 256, 256, 0, stream>>>(x, xb, n4);
    k_cast_w<<<256, 256, 0, stream>>>(W1, W2, W1b, W2b);
    k_agg1<<<gW, 256, 0, stream>>>(xb, offs, edata, dinv, ax, Nn);
    k_gemm_fused<<<gG, 256, 0, stream>>>(ax, W1b, b1v, W2b, h2, Nn);
    k_agg2_ln<<<gW, 256, 0, stream>>>(h2, offs, edata, dinv, b2v, gv, bev, out, Nn);
}

// Round 6
// 276.214 us; speedup vs baseline: 2.0435x; 1.1452x over previous
//
#include <hip/hip_runtime.h>

typedef unsigned short ushort_t;
typedef unsigned long long u64_t;
typedef __attribute__((ext_vector_type(8))) short short8;
typedef __attribute__((ext_vector_type(4))) float float4v;

__device__ inline float b2f(ushort_t u) {
    unsigned x = ((unsigned)u) << 16;
    return __builtin_bit_cast(float, x);
}
__device__ inline ushort_t f2b(float f) {
    unsigned x = __builtin_bit_cast(unsigned, f);
    unsigned r = (x + 0x7fffu + ((x >> 16) & 1u)) >> 16;
    return (ushort_t)r;
}

// ---------------- int64-vs-int32 edge_index layout detection ----------------

__global__ void k_mode(const int* __restrict__ ei, int E, int* mode) {
    __shared__ int any32;
    if (threadIdx.x == 0) any32 = 0;
    __syncthreads();
    for (int i = threadIdx.x; i < 1024; i += blockDim.x) {
        int slot = 2 * i + 1;
        if (slot < 2 * E && ei[slot] != 0) atomicOr(&any32, 1);
    }
    __syncthreads();
    if (threadIdx.x == 0) mode[0] = any32 ? 0 : 1;  // 1 => int64 layout
}

__device__ inline int ld_src(const int* __restrict__ ei, int e, int E, int m64) {
    return m64 ? ei[2 * (size_t)e] : ei[e];
}
__device__ inline int ld_dst(const int* __restrict__ ei, int e, int E, int m64) {
    return m64 ? ei[2 * ((size_t)E + e)] : ei[(size_t)E + e];
}

// ---------------- fp32 -> bf16 casts ----------------

__global__ void k_cast_x(const float* __restrict__ x, ushort_t* __restrict__ xb, int n4) {
    int i = blockIdx.x * blockDim.x + threadIdx.x;
    if (i >= n4) return;
    float4v v = ((const float4v*)x)[i];
    ushort4 o;
    o.x = f2b(v[0]); o.y = f2b(v[1]); o.z = f2b(v[2]); o.w = f2b(v[3]);
    ((ushort4*)xb)[i] = o;
}

__global__ void k_cast_w(const float* __restrict__ W1, const float* __restrict__ W2,
                         ushort_t* __restrict__ W1b, ushort_t* __restrict__ W2b) {
    int i = blockIdx.x * blockDim.x + threadIdx.x;  // 0..65535
    if (i < 32768) W1b[i] = f2b(W1[i]);
    else W2b[i - 32768] = f2b(W2[i - 32768]);
}

// ---------------- degree/CSR build ----------------
// packed[d]: high 32 = edge count, low 32 = sum(w) in 8.24 fixed point.
// One 64-bit atomic per edge; returned old high word = within-segment rank.

__global__ void k_node_init(u64_t* packed, int Nn) {
    int i = blockIdx.x * blockDim.x + threadIdx.x;
    if (i < Nn) packed[i] = 0ull;
}

__global__ void k_count(const int* __restrict__ ei, const float* __restrict__ w,
                        const int* __restrict__ mode,
                        u64_t* packed, int* __restrict__ rank, int E, int Nn) {
    int e = blockIdx.x * blockDim.x + threadIdx.x;
    if (e >= E) return;
    int m64 = mode[0];
    int s = ld_src(ei, e, E, m64);
    int d = ld_dst(ei, e, E, m64);
    if ((unsigned)s < (unsigned)Nn && (unsigned)d < (unsigned)Nn) {
        unsigned fx = (unsigned)(w[e] * 16777216.0f + 0.5f);
        u64_t old = atomicAdd(packed + d, (1ull << 32) | (u64_t)fx);
        rank[e] = (int)(old >> 32);
    } else {
        rank[e] = -1;
    }
}

__device__ inline int cnt_hi(const u64_t* packed, int i) {
    return ((const int*)packed)[2 * i + 1];  // little-endian high word
}

// ---------------- 3-phase multi-block exclusive scan over cnt_hi ----------------

__global__ __launch_bounds__(256) void k_scan_a(const u64_t* __restrict__ packed,
                                                int* __restrict__ bsum, int Nn) {
    int b = blockIdx.x, t = threadIdx.x;
    int base = b * 2048 + t * 8;
    int s = 0;
#pragma unroll
    for (int j = 0; j < 8; ++j) { int i = base + j; if (i < Nn) s += cnt_hi(packed, i); }
#pragma unroll
    for (int off = 1; off < 64; off <<= 1) s += __shfl_xor(s, off);
    __shared__ int wsum[4];
    if ((t & 63) == 0) wsum[t >> 6] = s;
    __syncthreads();
    if (t == 0) bsum[b] = wsum[0] + wsum[1] + wsum[2] + wsum[3];
}

// nb <= 64. One wave.
__global__ void k_scan_b(const int* __restrict__ bsum, int* __restrict__ bbase,
                         int nb, int* __restrict__ offs, int Nn) {
    int t = threadIdx.x;
    int own = (t < nb) ? bsum[t] : 0;
    int v = own;
#pragma unroll
    for (int off = 1; off < 64; off <<= 1) {
        int u = __shfl_up(v, off);
        if (t >= off) v += u;
    }
    if (t < nb) bbase[t] = v - own;  // exclusive
    if (t == 63) offs[Nn] = v;       // grand total
}

__global__ __launch_bounds__(256) void k_scan_c(const u64_t* __restrict__ packed,
                                                const int* __restrict__ bbase,
                                                int* __restrict__ offs, int Nn) {
    int b = blockIdx.x, t = threadIdx.x;
    int base = b * 2048 + t * 8;
    int v[8];
    int s = 0;
#pragma unroll
    for (int j = 0; j < 8; ++j) {
        int i = base + j;
        v[j] = (i < Nn) ? cnt_hi(packed, i) : 0;
        s += v[j];
    }
    __shared__ int sd[256];
    sd[t] = s;
    __syncthreads();
    for (int off = 1; off < 256; off <<= 1) {
        int u = (t >= off) ? sd[t - off] : 0;
        __syncthreads();
        sd[t] += u;
        __syncthreads();
    }
    int pos = bbase[b] + sd[t] - s;
#pragma unroll
    for (int j = 0; j < 8; ++j) {
        int i = base + j;
        if (i < Nn) { offs[i] = pos; pos += v[j]; }
    }
}

__global__ void k_dinv(const u64_t* __restrict__ packed, float* dinv, int Nn) {
    int i = blockIdx.x * blockDim.x + threadIdx.x;
    if (i >= Nn) return;
    float deg = 1.0f + (float)(unsigned)(packed[i] & 0xFFFFFFFFull) * (1.0f / 16777216.0f);
    dinv[i] = rsqrtf(deg);  // deg >= 1 (self loop)
}

// ---------------- scatter (atomic-free): edata[pos] = {src, bits(norm)} ----------------

__global__ void k_scatter(const int* __restrict__ ei, const float* __restrict__ w,
                          const int* __restrict__ mode,
                          const float* __restrict__ dinv,
                          const int* __restrict__ offs,
                          const int* __restrict__ rank,
                          int2* __restrict__ edata, int E, int Nn) {
    int e = blockIdx.x * blockDim.x + threadIdx.x;
    if (e >= E) return;
    int r = rank[e];
    if (r < 0) return;
    int m64 = mode[0];
    int s = ld_src(ei, e, E, m64);
    int d = ld_dst(ei, e, E, m64);
    int pos = offs[d] + r;
    float nw = dinv[s] * w[e] * dinv[d];
    int2 p;
    p.x = s;
    p.y = __builtin_bit_cast(int, nw);
    edata[pos] = p;
}

// ---------------- aggregation 1: ax = A_norm @ x  (bf16 in/out, fp32 acc) ----------------

__global__ __launch_bounds__(256) void k_agg1(const ushort_t* __restrict__ xb,
                                              const int* __restrict__ offs,
                                              const int2* __restrict__ edata,
                                              const float* __restrict__ dinv,
                                              ushort_t* __restrict__ ax, int Nn) {
    int v = (blockIdx.x * blockDim.x + threadIdx.x) >> 6;
    int lane = threadIdx.x & 63;
    if (v >= Nn) return;
    float dv = dinv[v];
    float sn = dv * dv;  // self-loop norm
    ushort2 p = ((const ushort2*)(xb + (size_t)v * 128))[lane];
    float a0 = b2f(p.x) * sn, a1 = b2f(p.y) * sn;
    int s = offs[v], e = offs[v + 1];
    int i = s;
    for (; i + 3 < e; i += 4) {
        int2 e0 = edata[i], e1 = edata[i + 1], e2 = edata[i + 2], e3 = edata[i + 3];
        float n0 = __builtin_bit_cast(float, e0.y);
        float n1 = __builtin_bit_cast(float, e1.y);
        float n2 = __builtin_bit_cast(float, e2.y);
        float n3 = __builtin_bit_cast(float, e3.y);
        ushort2 q0 = ((const ushort2*)(xb + (size_t)e0.x * 128))[lane];
        ushort2 q1 = ((const ushort2*)(xb + (size_t)e1.x * 128))[lane];
        ushort2 q2 = ((const ushort2*)(xb + (size_t)e2.x * 128))[lane];
        ushort2 q3 = ((const ushort2*)(xb + (size_t)e3.x * 128))[lane];
        a0 += b2f(q0.x) * n0; a1 += b2f(q0.y) * n0;
        a0 += b2f(q1.x) * n1; a1 += b2f(q1.y) * n1;
        a0 += b2f(q2.x) * n2; a1 += b2f(q2.y) * n2;
        a0 += b2f(q3.x) * n3; a1 += b2f(q3.y) * n3;
    }
    for (; i < e; ++i) {
        int2 ed = edata[i];
        float nw = __builtin_bit_cast(float, ed.y);
        ushort2 q = ((const ushort2*)(xb + (size_t)ed.x * 128))[lane];
        a0 += b2f(q.x) * nw;
        a1 += b2f(q.y) * nw;
    }
    ushort2 o; o.x = f2b(a0); o.y = f2b(a1);
    ((ushort2*)(ax + (size_t)v * 128))[lane] = o;
}

// ---------------- fused GEMM: h2 = relu(ax @ W1^T + b1) @ W2^T ----------------
// Block = 64 rows, 4 waves split the N dimension (no redundant W loads).
// Phase 1: wave w computes 64 rows x cols [w*64,w*64+64): W1 slice (4nt x 4kt)
// and a-frags (4mi x 4kt) fully prefetched into registers -> 32 loads in
// flight, one L2-latency exposure. ReLU'd 64x256 bf16 tile -> shared LDS.
// Phase 2: wave w computes 64 rows x cols [w*32,w*32+32) from LDS A-frags
// (ds_read_b128) and prefetched W2 slice (2nt x 8kt).
// MFMA 16x16x32 bf16 layouts: A row=lane&15,k=quad*8+j; B col=lane&15,
// k=quad*8+j; D col=lane&15,row=quad*4+reg.

__global__ __launch_bounds__(256, 2) void k_gemm_fused(const ushort_t* __restrict__ ax,
                                                       const ushort_t* __restrict__ W1b,
                                                       const float* __restrict__ b1v,
                                                       const ushort_t* __restrict__ W2b,
                                                       ushort_t* __restrict__ h2, int Nn) {
    __shared__ ushort_t tile[64][264];  // 33792 B; stride 264: 16B-aligned rows
    int tid = threadIdx.x, wid = tid >> 6, lane = tid & 63;
    int m = lane & 15, q = lane >> 4;
    int blk = blockIdx.x * 64;

    // ---- phase 1 prefetch: W1 slice + A rows ----
    short8 wf[4][4];  // [nt][kt]
#pragma unroll
    for (int nt = 0; nt < 4; ++nt) {
        const ushort_t* wb = W1b + (size_t)(wid * 64 + nt * 16 + m) * 128 + q * 8;
#pragma unroll
        for (int kt = 0; kt < 4; ++kt) wf[nt][kt] = *(const short8*)(wb + kt * 32);
    }
    short8 af[4][4];  // [mi][kt]
#pragma unroll
    for (int mi = 0; mi < 4; ++mi) {
        int arow = blk + mi * 16 + m;
        bool rv = arow < Nn;
        const ushort_t* ab = ax + (size_t)arow * 128 + q * 8;
#pragma unroll
        for (int kt = 0; kt < 4; ++kt)
            af[mi][kt] = rv ? *(const short8*)(ab + kt * 32) : (short8)0;
    }

    float4v acc1[4][4];  // [mi][nt]
#pragma unroll
    for (int mi = 0; mi < 4; ++mi)
#pragma unroll
        for (int nt = 0; nt < 4; ++nt) acc1[mi][nt] = (float4v){0.f, 0.f, 0.f, 0.f};

#pragma unroll
    for (int kt = 0; kt < 4; ++kt)
#pragma unroll
        for (int mi = 0; mi < 4; ++mi)
#pragma unroll
            for (int nt = 0; nt < 4; ++nt)
                acc1[mi][nt] = __builtin_amdgcn_mfma_f32_16x16x32_bf16(
                    af[mi][kt], wf[nt][kt], acc1[mi][nt], 0, 0, 0);

    // ---- epilogue 1: bias + ReLU -> shared LDS tile ----
#pragma unroll
    for (int nt = 0; nt < 4; ++nt) {
        int col = wid * 64 + nt * 16 + m;
        float bb = b1v[col];
#pragma unroll
        for (int mi = 0; mi < 4; ++mi) {
#pragma unroll
            for (int r = 0; r < 4; ++r) {
                float v = acc1[mi][nt][r] + bb;
                v = v > 0.f ? v : 0.f;
                tile[mi * 16 + q * 4 + r][col] = f2b(v);
            }
        }
    }
    __syncthreads();

    // ---- phase 2 prefetch: W2 slice ----
    short8 w2f[2][8];  // [n2][kt]
#pragma unroll
    for (int n2 = 0; n2 < 2; ++n2) {
        const ushort_t* wb = W2b + (size_t)(wid * 32 + n2 * 16 + m) * 256 + q * 8;
#pragma unroll
        for (int kt = 0; kt < 8; ++kt) w2f[n2][kt] = *(const short8*)(wb + kt * 32);
    }

    float4v acc2[4][2];  // [mi][n2]
#pragma unroll
    for (int mi = 0; mi < 4; ++mi)
#pragma unroll
        for (int n2 = 0; n2 < 2; ++n2) acc2[mi][n2] = (float4v){0.f, 0.f, 0.f, 0.f};

#pragma unroll
    for (int kt = 0; kt < 8; ++kt) {
#pragma unroll
        for (int mi = 0; mi < 4; ++mi) {
            short8 a2 = *(const short8*)&tile[mi * 16 + m][kt * 32 + q * 8];
#pragma unroll
            for (int n2 = 0; n2 < 2; ++n2)
                acc2[mi][n2] = __builtin_amdgcn_mfma_f32_16x16x32_bf16(
                    a2, w2f[n2][kt], acc2[mi][n2], 0, 0, 0);
        }
    }

    // ---- epilogue 2: store h2 (bf16) ----
#pragma unroll
    for (int mi = 0; mi < 4; ++mi) {
#pragma unroll
        for (int n2 = 0; n2 < 2; ++n2) {
            int col = wid * 32 + n2 * 16 + m;
#pragma unroll
            for (int r = 0; r < 4; ++r) {
                int row = blk + mi * 16 + q * 4 + r;
                if (row < Nn) h2[(size_t)row * 128 + col] = f2b(acc2[mi][n2][r]);
            }
        }
    }
}

// ---------------- aggregation 2 + bias + LayerNorm (fp32 out) ----------------

__global__ __launch_bounds__(256) void k_agg2_ln(const ushort_t* __restrict__ h2,
                                                 const int* __restrict__ offs,
                                                 const int2* __restrict__ edata,
                                                 const float* __restrict__ dinv,
                                                 const float* __restrict__ b2v,
                                                 const float* __restrict__ gv,
                                                 const float* __restrict__ bev,
                                                 float* __restrict__ out, int Nn) {
    int v = (blockIdx.x * blockDim.x + threadIdx.x) >> 6;
    int lane = threadIdx.x & 63;
    if (v >= Nn) return;
    float dv = dinv[v];
    float sn = dv * dv;
    ushort2 p = ((const ushort2*)(h2 + (size_t)v * 128))[lane];
    float a0 = b2f(p.x) * sn, a1 = b2f(p.y) * sn;
    int s = offs[v], e = offs[v + 1];
    int i = s;
    for (; i + 3 < e; i += 4) {
        int2 e0 = edata[i], e1 = edata[i + 1], e2 = edata[i + 2], e3 = edata[i + 3];
        float n0 = __builtin_bit_cast(float, e0.y);
        float n1 = __builtin_bit_cast(float, e1.y);
        float n2 = __builtin_bit_cast(float, e2.y);
        float n3 = __builtin_bit_cast(float, e3.y);
        ushort2 q0 = ((const ushort2*)(h2 + (size_t)e0.x * 128))[lane];
        ushort2 q1 = ((const ushort2*)(h2 + (size_t)e1.x * 128))[lane];
        ushort2 q2 = ((const ushort2*)(h2 + (size_t)e2.x * 128))[lane];
        ushort2 q3 = ((const ushort2*)(h2 + (size_t)e3.x * 128))[lane];
        a0 += b2f(q0.x) * n0; a1 += b2f(q0.y) * n0;
        a0 += b2f(q1.x) * n1; a1 += b2f(q1.y) * n1;
        a0 += b2f(q2.x) * n2; a1 += b2f(q2.y) * n2;
        a0 += b2f(q3.x) * n3; a1 += b2f(q3.y) * n3;
    }
    for (; i < e; ++i) {
        int2 ed = edata[i];
        float nw = __builtin_bit_cast(float, ed.y);
        ushort2 q = ((const ushort2*)(h2 + (size_t)ed.x * 128))[lane];
        a0 += b2f(q.x) * nw;
        a1 += b2f(q.y) * nw;
    }
    int d0 = lane * 2;
    a0 += b2v[d0];
    a1 += b2v[d0 + 1];
    float ssum = a0 + a1, ssq = a0 * a0 + a1 * a1;
#pragma unroll
    for (int off = 1; off < 64; off <<= 1) {
        ssum += __shfl_xor(ssum, off);
        ssq += __shfl_xor(ssq, off);
    }
    float mu = ssum * (1.0f / 128.0f);
    float var = ssq * (1.0f / 128.0f) - mu * mu;
    float r = rsqrtf(var + 1e-5f);
    float2 o;
    o.x = (a0 - mu) * r * gv[d0] + bev[d0];
    o.y = (a1 - mu) * r * gv[d0 + 1] + bev[d0 + 1];
    ((float2*)(out + (size_t)v * 128))[lane] = o;
}

// ---------------- launch ----------------

extern "C" void kernel_launch(void* const* d_in, const int* in_sizes, int n_in,
                              void* d_out, int out_size, void* d_ws, size_t ws_size,
                              hipStream_t stream) {
    const float* x   = (const float*)d_in[0];  // [N,128] f32
    const int*   ei  = (const int*)d_in[1];    // [2,E] int32/int64 (detected)
    const float* ew  = (const float*)d_in[2];  // [E] f32
    const float* W1  = (const float*)d_in[3];  // [256,128] f32
    const float* b1v = (const float*)d_in[4];  // [256]
    const float* W2  = (const float*)d_in[5];  // [128,256]
    const float* b2v = (const float*)d_in[6];  // [128]
    const float* gv  = (const float*)d_in[7];  // [128]
    const float* bev = (const float*)d_in[8];  // [128]
    float* out = (float*)d_out;

    const int Nn = in_sizes[0] / 128;
    const int E  = in_sizes[2];

    char* base = (char*)d_ws;
    size_t off = 0;
    auto alloc = [&](size_t bytes) {
        char* p = base + off;
        off = (off + bytes + 255) & ~(size_t)255;
        return p;
    };
    int*    mode   = (int*)alloc(4);
    u64_t*  packed = (u64_t*)alloc((size_t)Nn * 8);
    float*  dinv   = (float*)alloc((size_t)Nn * 4);
    int*    offs   = (int*)alloc((size_t)(Nn + 1) * 4);
    int*    bsum   = (int*)alloc(64 * 4);
    int*    bbase  = (int*)alloc(64 * 4);
    int*    rank   = (int*)alloc((size_t)E * 4);
    int2*   edata  = (int2*)alloc((size_t)E * 8);
    ushort_t* xb   = (ushort_t*)alloc((size_t)Nn * 128 * 2);
    ushort_t* h2   = (ushort_t*)alloc((size_t)Nn * 128 * 2);
    ushort_t* W1b  = (ushort_t*)alloc(32768 * 2);
    ushort_t* W2b  = (ushort_t*)alloc(32768 * 2);
    ushort_t* ax   = (ushort_t*)d_out;  // stage ax in d_out; dead before final write
    (void)ws_size; (void)n_in; (void)out_size;

    int gN = (Nn + 255) / 256;
    int gE = (E + 255) / 256;
    int gW = (Nn + 3) / 4;        // wave per node
    int gG = (Nn + 63) / 64;      // 64 rows per block
    int n4 = Nn * 128 / 4;
    int nb = (Nn + 2047) / 2048;  // scan blocks (<= 64)

    k_mode<<<1, 256, 0, stream>>>(ei, E, mode);
    k_node_init<<<gN, 256, 0, stream>>>(packed, Nn);
    k_count<<<gE, 256, 0, stream>>>(ei, ew, mode, packed, rank, E, Nn);
    k_scan_a<<<nb, 256, 0, stream>>>(packed, bsum, Nn);
    k_scan_b<<<1, 64, 0, stream>>>(bsum, bbase, nb, offs, Nn);
    k_scan_c<<<nb, 256, 0, stream>>>(packed, bbase, offs, Nn);
    k_dinv<<<gN, 256, 0, stream>>>(packed, dinv, Nn);
    k_scatter<<<gE, 256, 0, stream>>>(ei, ew, mode, dinv, offs, rank, edata, E, Nn);
    k_cast_x<<<(n4 + 255) / 256, 256, 0, stream>>>(x, xb, n4);
    k_cast_w<<<256, 256, 0, stream>>>(W1, W2, W1b, W2b);
    k_agg1<<<gW, 256, 0, stream>>>(xb, offs, edata, dinv, ax, Nn);
    k_gemm_fused<<<gG, 256, 0, stream>>>(ax, W1b, b1v, W2b, h2, Nn);
    k_agg2_ln<<<gW, 256, 0, stream>>>(h2, offs, edata, dinv, b2v, gv, bev, out, Nn);
}

// Round 7
// 271.088 us; speedup vs baseline: 2.0822x; 1.0189x over previous
//
#include <hip/hip_runtime.h>

typedef unsigned short ushort_t;
typedef unsigned long long u64_t;
typedef __attribute__((ext_vector_type(8))) short short8;
typedef __attribute__((ext_vector_type(4))) float float4v;

__device__ inline float b2f(ushort_t u) {
    unsigned x = ((unsigned)u) << 16;
    return __builtin_bit_cast(float, x);
}
__device__ inline ushort_t f2b(float f) {
    unsigned x = __builtin_bit_cast(unsigned, f);
    unsigned r = (x + 0x7fffu + ((x >> 16) & 1u)) >> 16;
    return (ushort_t)r;
}

// ---------------- int64-vs-int32 edge_index layout detection ----------------

__global__ void k_mode(const int* __restrict__ ei, int E, int* mode) {
    __shared__ int any32;
    if (threadIdx.x == 0) any32 = 0;
    __syncthreads();
    for (int i = threadIdx.x; i < 1024; i += blockDim.x) {
        int slot = 2 * i + 1;
        if (slot < 2 * E && ei[slot] != 0) atomicOr(&any32, 1);
    }
    __syncthreads();
    if (threadIdx.x == 0) mode[0] = any32 ? 0 : 1;  // 1 => int64 layout
}

__device__ inline int ld_src(const int* __restrict__ ei, int e, int E, int m64) {
    return m64 ? ei[2 * (size_t)e] : ei[e];
}
__device__ inline int ld_dst(const int* __restrict__ ei, int e, int E, int m64) {
    return m64 ? ei[2 * ((size_t)E + e)] : ei[(size_t)E + e];
}

// ---------------- fp32 -> bf16 casts ----------------

__global__ void k_cast_x(const float* __restrict__ x, ushort_t* __restrict__ xb, int n4) {
    int i = blockIdx.x * blockDim.x + threadIdx.x;
    if (i >= n4) return;
    float4v v = ((const float4v*)x)[i];
    ushort4 o;
    o.x = f2b(v[0]); o.y = f2b(v[1]); o.z = f2b(v[2]); o.w = f2b(v[3]);
    ((ushort4*)xb)[i] = o;
}

__global__ void k_cast_w(const float* __restrict__ W1, const float* __restrict__ W2,
                         ushort_t* __restrict__ W1b, ushort_t* __restrict__ W2b) {
    int i = blockIdx.x * blockDim.x + threadIdx.x;  // 0..65535
    if (i < 32768) W1b[i] = f2b(W1[i]);
    else W2b[i - 32768] = f2b(W2[i - 32768]);
}

// ---------------- degree/CSR build ----------------
// packed[d]: high 32 = edge count, low 32 = sum(w) in 8.24 fixed point.
// One 64-bit atomic per edge; returned old high word = within-segment rank.

__global__ void k_node_init(u64_t* packed, int Nn) {
    int i = blockIdx.x * blockDim.x + threadIdx.x;
    if (i < Nn) packed[i] = 0ull;
}

__global__ void k_count(const int* __restrict__ ei, const float* __restrict__ w,
                        const int* __restrict__ mode,
                        u64_t* packed, int* __restrict__ rank, int E, int Nn) {
    int e = blockIdx.x * blockDim.x + threadIdx.x;
    if (e >= E) return;
    int m64 = mode[0];
    int s = ld_src(ei, e, E, m64);
    int d = ld_dst(ei, e, E, m64);
    if ((unsigned)s < (unsigned)Nn && (unsigned)d < (unsigned)Nn) {
        unsigned fx = (unsigned)(w[e] * 16777216.0f + 0.5f);
        u64_t old = atomicAdd(packed + d, (1ull << 32) | (u64_t)fx);
        rank[e] = (int)(old >> 32);
    } else {
        rank[e] = -1;
    }
}

__device__ inline int cnt_hi(const u64_t* packed, int i) {
    return ((const int*)packed)[2 * i + 1];  // little-endian high word
}

// ---------------- 3-phase multi-block exclusive scan over cnt_hi ----------------

__global__ __launch_bounds__(256) void k_scan_a(const u64_t* __restrict__ packed,
                                                int* __restrict__ bsum, int Nn) {
    int b = blockIdx.x, t = threadIdx.x;
    int base = b * 2048 + t * 8;
    int s = 0;
#pragma unroll
    for (int j = 0; j < 8; ++j) { int i = base + j; if (i < Nn) s += cnt_hi(packed, i); }
#pragma unroll
    for (int off = 1; off < 64; off <<= 1) s += __shfl_xor(s, off);
    __shared__ int wsum[4];
    if ((t & 63) == 0) wsum[t >> 6] = s;
    __syncthreads();
    if (t == 0) bsum[b] = wsum[0] + wsum[1] + wsum[2] + wsum[3];
}

// nb <= 64. One wave.
__global__ void k_scan_b(const int* __restrict__ bsum, int* __restrict__ bbase,
                         int nb, int* __restrict__ offs, int Nn) {
    int t = threadIdx.x;
    int own = (t < nb) ? bsum[t] : 0;
    int v = own;
#pragma unroll
    for (int off = 1; off < 64; off <<= 1) {
        int u = __shfl_up(v, off);
        if (t >= off) v += u;
    }
    if (t < nb) bbase[t] = v - own;  // exclusive
    if (t == 63) offs[Nn] = v;       // grand total
}

__global__ __launch_bounds__(256) void k_scan_c(const u64_t* __restrict__ packed,
                                                const int* __restrict__ bbase,
                                                int* __restrict__ offs, int Nn) {
    int b = blockIdx.x, t = threadIdx.x;
    int base = b * 2048 + t * 8;
    int v[8];
    int s = 0;
#pragma unroll
    for (int j = 0; j < 8; ++j) {
        int i = base + j;
        v[j] = (i < Nn) ? cnt_hi(packed, i) : 0;
        s += v[j];
    }
    __shared__ int sd[256];
    sd[t] = s;
    __syncthreads();
    for (int off = 1; off < 256; off <<= 1) {
        int u = (t >= off) ? sd[t - off] : 0;
        __syncthreads();
        sd[t] += u;
        __syncthreads();
    }
    int pos = bbase[b] + sd[t] - s;
#pragma unroll
    for (int j = 0; j < 8; ++j) {
        int i = base + j;
        if (i < Nn) { offs[i] = pos; pos += v[j]; }
    }
}

__global__ void k_dinv(const u64_t* __restrict__ packed, float* dinv, int Nn) {
    int i = blockIdx.x * blockDim.x + threadIdx.x;
    if (i >= Nn) return;
    float deg = 1.0f + (float)(unsigned)(packed[i] & 0xFFFFFFFFull) * (1.0f / 16777216.0f);
    dinv[i] = rsqrtf(deg);  // deg >= 1 (self loop)
}

// ---------------- scatter (atomic-free): edata[pos] = {src, bits(norm)} ----------------

__global__ void k_scatter(const int* __restrict__ ei, const float* __restrict__ w,
                          const int* __restrict__ mode,
                          const float* __restrict__ dinv,
                          const int* __restrict__ offs,
                          const int* __restrict__ rank,
                          int2* __restrict__ edata, int E, int Nn) {
    int e = blockIdx.x * blockDim.x + threadIdx.x;
    if (e >= E) return;
    int r = rank[e];
    if (r < 0) return;
    int m64 = mode[0];
    int s = ld_src(ei, e, E, m64);
    int d = ld_dst(ei, e, E, m64);
    int pos = offs[d] + r;
    float nw = dinv[s] * w[e] * dinv[d];
    int2 p;
    p.x = s;
    p.y = __builtin_bit_cast(int, nw);
    edata[pos] = p;
}

// ---------------- split-wave gather aggregation ----------------
// Wave per node. Half p = lane>>5 handles edges i+p, i+p+2, ... Each lane
// loads ushort4 (8 B): 32 lanes cover a 256 B row, so one VMEM instruction
// fetches TWO rows -> 8 rows in flight at unroll 4. Tail edges clamp to
// min(idx,e-1) (duplicate line, free) with norm zeroed. shfl_xor(32) merges
// the halves at the end.

__device__ inline void agg_edges(const ushort_t* __restrict__ src,
                                 const int2* __restrict__ edata,
                                 int s, int e, int hl, int p, float* a) {
    int i = s;
    for (; i + 7 < e; i += 8) {
#pragma unroll
        for (int j = 0; j < 4; ++j) {
            int idx = i + p + 2 * j;
            int2 ed = edata[idx];
            float nw = __builtin_bit_cast(float, ed.y);
            ushort4 q = ((const ushort4*)(src + (size_t)ed.x * 128))[hl];
            a[0] += b2f(q.x) * nw; a[1] += b2f(q.y) * nw;
            a[2] += b2f(q.z) * nw; a[3] += b2f(q.w) * nw;
        }
    }
    for (; i < e; i += 2) {
        int idx = i + p;
        int ic = min(idx, e - 1);
        int2 ed = edata[ic];
        float nw = (idx < e) ? __builtin_bit_cast(float, ed.y) : 0.f;
        ushort4 q = ((const ushort4*)(src + (size_t)ed.x * 128))[hl];
        a[0] += b2f(q.x) * nw; a[1] += b2f(q.y) * nw;
        a[2] += b2f(q.z) * nw; a[3] += b2f(q.w) * nw;
    }
}

// aggregation 1: ax = A_norm @ x  (bf16 in/out, fp32 acc)
__global__ __launch_bounds__(256) void k_agg1(const ushort_t* __restrict__ xb,
                                              const int* __restrict__ offs,
                                              const int2* __restrict__ edata,
                                              const float* __restrict__ dinv,
                                              ushort_t* __restrict__ ax, int Nn) {
    int v = (blockIdx.x * blockDim.x + threadIdx.x) >> 6;
    int lane = threadIdx.x & 63;
    if (v >= Nn) return;
    int hl = lane & 31, p = lane >> 5;
    float a[4] = {0.f, 0.f, 0.f, 0.f};
    if (p == 0) {  // self-loop in half 0 only
        float dv = dinv[v];
        float sn = dv * dv;
        ushort4 pq = ((const ushort4*)(xb + (size_t)v * 128))[hl];
        a[0] = b2f(pq.x) * sn; a[1] = b2f(pq.y) * sn;
        a[2] = b2f(pq.z) * sn; a[3] = b2f(pq.w) * sn;
    }
    int s = offs[v], e = offs[v + 1];
    agg_edges(xb, edata, s, e, hl, p, a);
#pragma unroll
    for (int j = 0; j < 4; ++j) a[j] += __shfl_xor(a[j], 32);
    if (p == 0) {
        ushort4 o;
        o.x = f2b(a[0]); o.y = f2b(a[1]); o.z = f2b(a[2]); o.w = f2b(a[3]);
        ((ushort4*)(ax + (size_t)v * 128))[hl] = o;
    }
}

// ---------------- fused GEMM: h2 = relu(ax @ W1^T + b1) @ W2^T ----------------
// Block = 64 rows, 4 waves split the N dimension (no redundant W loads).
// Phase 1: wave w computes 64 rows x cols [w*64,w*64+64): W1 slice + a-frags
// fully prefetched into registers. ReLU'd 64x256 bf16 tile -> shared LDS.
// Phase 2: wave w computes 64 rows x cols [w*32,w*32+32) from LDS A-frags
// and prefetched W2 slice. MFMA 16x16x32 bf16 layouts: A row=lane&15,
// k=quad*8+j; B col=lane&15, k=quad*8+j; D col=lane&15, row=quad*4+reg.

__global__ __launch_bounds__(256, 2) void k_gemm_fused(const ushort_t* __restrict__ ax,
                                                       const ushort_t* __restrict__ W1b,
                                                       const float* __restrict__ b1v,
                                                       const ushort_t* __restrict__ W2b,
                                                       ushort_t* __restrict__ h2, int Nn) {
    __shared__ ushort_t tile[64][264];  // 33792 B; stride 264: 16B-aligned rows
    int tid = threadIdx.x, wid = tid >> 6, lane = tid & 63;
    int m = lane & 15, q = lane >> 4;
    int blk = blockIdx.x * 64;

    short8 wf[4][4];  // [nt][kt]
#pragma unroll
    for (int nt = 0; nt < 4; ++nt) {
        const ushort_t* wb = W1b + (size_t)(wid * 64 + nt * 16 + m) * 128 + q * 8;
#pragma unroll
        for (int kt = 0; kt < 4; ++kt) wf[nt][kt] = *(const short8*)(wb + kt * 32);
    }
    short8 af[4][4];  // [mi][kt]
#pragma unroll
    for (int mi = 0; mi < 4; ++mi) {
        int arow = blk + mi * 16 + m;
        bool rv = arow < Nn;
        const ushort_t* ab = ax + (size_t)arow * 128 + q * 8;
#pragma unroll
        for (int kt = 0; kt < 4; ++kt)
            af[mi][kt] = rv ? *(const short8*)(ab + kt * 32) : (short8)0;
    }

    float4v acc1[4][4];  // [mi][nt]
#pragma unroll
    for (int mi = 0; mi < 4; ++mi)
#pragma unroll
        for (int nt = 0; nt < 4; ++nt) acc1[mi][nt] = (float4v){0.f, 0.f, 0.f, 0.f};

#pragma unroll
    for (int kt = 0; kt < 4; ++kt)
#pragma unroll
        for (int mi = 0; mi < 4; ++mi)
#pragma unroll
            for (int nt = 0; nt < 4; ++nt)
                acc1[mi][nt] = __builtin_amdgcn_mfma_f32_16x16x32_bf16(
                    af[mi][kt], wf[nt][kt], acc1[mi][nt], 0, 0, 0);

#pragma unroll
    for (int nt = 0; nt < 4; ++nt) {
        int col = wid * 64 + nt * 16 + m;
        float bb = b1v[col];
#pragma unroll
        for (int mi = 0; mi < 4; ++mi) {
#pragma unroll
            for (int r = 0; r < 4; ++r) {
                float v = acc1[mi][nt][r] + bb;
                v = v > 0.f ? v : 0.f;
                tile[mi * 16 + q * 4 + r][col] = f2b(v);
            }
        }
    }
    __syncthreads();

    short8 w2f[2][8];  // [n2][kt]
#pragma unroll
    for (int n2 = 0; n2 < 2; ++n2) {
        const ushort_t* wb = W2b + (size_t)(wid * 32 + n2 * 16 + m) * 256 + q * 8;
#pragma unroll
        for (int kt = 0; kt < 8; ++kt) w2f[n2][kt] = *(const short8*)(wb + kt * 32);
    }

    float4v acc2[4][2];  // [mi][n2]
#pragma unroll
    for (int mi = 0; mi < 4; ++mi)
#pragma unroll
        for (int n2 = 0; n2 < 2; ++n2) acc2[mi][n2] = (float4v){0.f, 0.f, 0.f, 0.f};

#pragma unroll
    for (int kt = 0; kt < 8; ++kt) {
#pragma unroll
        for (int mi = 0; mi < 4; ++mi) {
            short8 a2 = *(const short8*)&tile[mi * 16 + m][kt * 32 + q * 8];
#pragma unroll
            for (int n2 = 0; n2 < 2; ++n2)
                acc2[mi][n2] = __builtin_amdgcn_mfma_f32_16x16x32_bf16(
                    a2, w2f[n2][kt], acc2[mi][n2], 0, 0, 0);
        }
    }

#pragma unroll
    for (int mi = 0; mi < 4; ++mi) {
#pragma unroll
        for (int n2 = 0; n2 < 2; ++n2) {
            int col = wid * 32 + n2 * 16 + m;
#pragma unroll
            for (int r = 0; r < 4; ++r) {
                int row = blk + mi * 16 + q * 4 + r;
                if (row < Nn) h2[(size_t)row * 128 + col] = f2b(acc2[mi][n2][r]);
            }
        }
    }
}

// ---------------- aggregation 2 + bias + LayerNorm (fp32 out) ----------------

__global__ __launch_bounds__(256) void k_agg2_ln(const ushort_t* __restrict__ h2,
                                                 const int* __restrict__ offs,
                                                 const int2* __restrict__ edata,
                                                 const float* __restrict__ dinv,
                                                 const float* __restrict__ b2v,
                                                 const float* __restrict__ gv,
                                                 const float* __restrict__ bev,
                                                 float* __restrict__ out, int Nn) {
    int v = (blockIdx.x * blockDim.x + threadIdx.x) >> 6;
    int lane = threadIdx.x & 63;
    if (v >= Nn) return;
    int hl = lane & 31, p = lane >> 5;
    float a[4] = {0.f, 0.f, 0.f, 0.f};
    if (p == 0) {
        float dv = dinv[v];
        float sn = dv * dv;
        ushort4 pq = ((const ushort4*)(h2 + (size_t)v * 128))[hl];
        a[0] = b2f(pq.x) * sn; a[1] = b2f(pq.y) * sn;
        a[2] = b2f(pq.z) * sn; a[3] = b2f(pq.w) * sn;
    }
    int s = offs[v], e = offs[v + 1];
    agg_edges(h2, edata, s, e, hl, p, a);
#pragma unroll
    for (int j = 0; j < 4; ++j) a[j] += __shfl_xor(a[j], 32);

    int d0 = hl * 4;
#pragma unroll
    for (int j = 0; j < 4; ++j) a[j] += b2v[d0 + j];

    // every dim held twice (both halves) -> divide by 256
    float ssum = a[0] + a[1] + a[2] + a[3];
    float ssq = a[0] * a[0] + a[1] * a[1] + a[2] * a[2] + a[3] * a[3];
#pragma unroll
    for (int off = 1; off < 64; off <<= 1) {
        ssum += __shfl_xor(ssum, off);
        ssq += __shfl_xor(ssq, off);
    }
    float mu = ssum * (1.0f / 256.0f);
    float var = ssq * (1.0f / 256.0f) - mu * mu;
    float r = rsqrtf(var + 1e-5f);
    if (p == 0) {
        float4v o;
#pragma unroll
        for (int j = 0; j < 4; ++j)
            o[j] = (a[j] - mu) * r * gv[d0 + j] + bev[d0 + j];
        ((float4v*)(out + (size_t)v * 128))[hl] = o;
    }
}

// ---------------- launch ----------------

extern "C" void kernel_launch(void* const* d_in, const int* in_sizes, int n_in,
                              void* d_out, int out_size, void* d_ws, size_t ws_size,
                              hipStream_t stream) {
    const float* x   = (const float*)d_in[0];  // [N,128] f32
    const int*   ei  = (const int*)d_in[1];    // [2,E] int32/int64 (detected)
    const float* ew  = (const float*)d_in[2];  // [E] f32
    const float* W1  = (const float*)d_in[3];  // [256,128] f32
    const float* b1v = (const float*)d_in[4];  // [256]
    const float* W2  = (const float*)d_in[5];  // [128,256]
    const float* b2v = (const float*)d_in[6];  // [128]
    const float* gv  = (const float*)d_in[7];  // [128]
    const float* bev = (const float*)d_in[8];  // [128]
    float* out = (float*)d_out;

    const int Nn = in_sizes[0] / 128;
    const int E  = in_sizes[2];

    char* base = (char*)d_ws;
    size_t off = 0;
    auto alloc = [&](size_t bytes) {
        char* p = base + off;
        off = (off + bytes + 255) & ~(size_t)255;
        return p;
    };
    int*    mode   = (int*)alloc(4);
    u64_t*  packed = (u64_t*)alloc((size_t)Nn * 8);
    float*  dinv   = (float*)alloc((size_t)Nn * 4);
    int*    offs   = (int*)alloc((size_t)(Nn + 1) * 4);
    int*    bsum   = (int*)alloc(64 * 4);
    int*    bbase  = (int*)alloc(64 * 4);
    int*    rank   = (int*)alloc((size_t)E * 4);
    int2*   edata  = (int2*)alloc((size_t)E * 8);
    ushort_t* xb   = (ushort_t*)alloc((size_t)Nn * 128 * 2);
    ushort_t* h2   = (ushort_t*)alloc((size_t)Nn * 128 * 2);
    ushort_t* W1b  = (ushort_t*)alloc(32768 * 2);
    ushort_t* W2b  = (ushort_t*)alloc(32768 * 2);
    ushort_t* ax   = (ushort_t*)d_out;  // stage ax in d_out; dead before final write
    (void)ws_size; (void)n_in; (void)out_size;

    int gN = (Nn + 255) / 256;
    int gE = (E + 255) / 256;
    int gW = (Nn + 3) / 4;        // wave per node
    int gG = (Nn + 63) / 64;      // 64 rows per block
    int n4 = Nn * 128 / 4;
    int nb = (Nn + 2047) / 2048;  // scan blocks (<= 64)

    k_mode<<<1, 256, 0, stream>>>(ei, E, mode);
    k_node_init<<<gN, 256, 0, stream>>>(packed, Nn);
    k_count<<<gE, 256, 0, stream>>>(ei, ew, mode, packed, rank, E, Nn);
    k_scan_a<<<nb, 256, 0, stream>>>(packed, bsum, Nn);
    k_scan_b<<<1, 64, 0, stream>>>(bsum, bbase, nb, offs, Nn);
    k_scan_c<<<nb, 256, 0, stream>>>(packed, bbase, offs, Nn);
    k_dinv<<<gN, 256, 0, stream>>>(packed, dinv, Nn);
    k_scatter<<<gE, 256, 0, stream>>>(ei, ew, mode, dinv, offs, rank, edata, E, Nn);
    k_cast_x<<<(n4 + 255) / 256, 256, 0, stream>>>(x, xb, n4);
    k_cast_w<<<256, 256, 0, stream>>>(W1, W2, W1b, W2b);
    k_agg1<<<gW, 256, 0, stream>>>(xb, offs, edata, dinv, ax, Nn);
    k_gemm_fused<<<gG, 256, 0, stream>>>(ax, W1b, b1v, W2b, h2, Nn);
    k_agg2_ln<<<gW, 256, 0, stream>>>(h2, offs, edata, dinv, b2v, gv, bev, out, Nn);
}